// Round 4
// baseline (155.955 us; speedup 1.0000x reference)
//
#include <hip/hip_runtime.h>
#include <hip/hip_bf16.h>
#include <math.h>

// Problem constants: B=64, H=192, W=192, STRIDE=8, EPS=1e-7
#define STRIDE_F 8.0f
#define EPS_F 1e-7f
#define PI_2_F 1.57079632679489662f

#define NBLOCKS 1152   // (64*192*192/8) / 256

__device__ __forceinline__ float frcp(float x) { return __builtin_amdgcn_rcpf(x); }

// atan(w/h) for w >= 0, h > 0, branch-free min/max range reduction,
// degree-11 odd minimax poly, max err ~1e-5 rad (tolerance is 1.56e-2).
__device__ __forceinline__ float fast_atan_ratio(float w, float h)
{
    float num = fminf(w, h);
    float den = fmaxf(w, h);
    float z   = num * frcp(den);
    float z2  = z * z;
    float p = fmaf(z2, -0.0117212f,  0.05265332f);
    p = fmaf(z2, p, -0.11643287f);
    p = fmaf(z2, p,  0.19354346f);
    p = fmaf(z2, p, -0.33262347f);
    p = fmaf(z2, p,  0.99997726f);
    p = z * p;
    return (w > h) ? (PI_2_F - p) : p;
}

__device__ __forceinline__ void ciou_elem(
    float cx, float cy,
    float pl, float pt, float pr, float pb,
    float tl, float tt, float tr, float tb,
    int m_i, float& ls, float& ms)
{
    float px1 = cx - pl * STRIDE_F;
    float py1 = cy - pt * STRIDE_F;
    float px2 = cx + pr * STRIDE_F;
    float py2 = cy + pb * STRIDE_F;
    float tx1 = cx - tl * STRIDE_F;
    float ty1 = cy - tt * STRIDE_F;
    float tx2 = cx + tr * STRIDE_F;
    float ty2 = cy + tb * STRIDE_F;

    float w1 = px2 - px1, h1 = py2 - py1;
    float w2 = tx2 - tx1, h2 = ty2 - ty1;
    float iw = fmaxf(fminf(px2, tx2) - fmaxf(px1, tx1), 0.0f);
    float ih = fmaxf(fminf(py2, ty2) - fmaxf(py1, ty1), 0.0f);
    float inter = iw * ih;
    float uni   = w1 * h1 + w2 * h2 - inter + EPS_F;
    float iou   = inter * frcp(uni);

    float cw = fmaxf(px2, tx2) - fminf(px1, tx1);
    float ch = fmaxf(py2, ty2) - fminf(py1, ty1);
    float c2 = cw * cw + ch * ch + EPS_F;

    float dx = tx1 + tx2 - px1 - px2;
    float dy = ty1 + ty2 - py1 - py2;
    float rho2 = (dx * dx + dy * dy) * 0.25f;

    const float FOUR_OVER_PI2 = 0.40528473456935109f; // 4/pi^2
    float dv = fast_atan_ratio(w2, h2 + EPS_F) - fast_atan_ratio(w1, h1 + EPS_F);
    float v  = FOUR_OVER_PI2 * dv * dv;
    float alpha = v * frcp(v - iou + (1.0f + EPS_F));
    float ciou  = iou - rho2 * frcp(c2) - alpha * v;

    float m = (m_i != 0) ? 1.0f : 0.0f;
    ls += (1.0f - ciou) * m;
    ms += m;
}

// One fused kernel: per-block partials + last-block final reduction
// (rocPRIM-style ticket). parts/ticket live in d_ws; ticket is zeroed
// each call via hipMemsetAsync (graph-capture safe).
__global__ __launch_bounds__(256) void ciou_loss_kernel(
    const float4* __restrict__ pred, const float4* __restrict__ tgt,
    const int4* __restrict__ mask, float2* __restrict__ parts,
    unsigned int* __restrict__ ticket, float* __restrict__ out)
{
    const int HW4 = 9216;  // 192*192/4
    const int W4  = 48;    // 192/4
    const int HW8 = 4608;  // HW/8
    const int W8  = 24;    // W/8

    int idx8 = blockIdx.x * blockDim.x + threadIdx.x;  // exact: 1152*256*8 == total
    int bb  = idx8 / HW8;
    int hw8 = idx8 - bb * HW8;
    int h   = hw8 / W8;
    int w8  = hw8 - h * W8;

    float cy  = ((float)h + 0.5f) * STRIDE_F;
    float cx0 = ((float)(w8 * 8) + 0.5f) * STRIDE_F;

    // float4 index of the first of two consecutive float4s
    size_t base4 = (size_t)bb * 4 * HW4 + (size_t)h * W4 + (size_t)w8 * 2;
    size_t m4    = (size_t)bb * HW4 + (size_t)h * W4 + (size_t)w8 * 2;

    float4 pl4a = pred[base4];
    float4 pl4b = pred[base4 + 1];
    float4 pt4a = pred[base4 + HW4];
    float4 pt4b = pred[base4 + HW4 + 1];
    float4 pr4a = pred[base4 + 2 * HW4];
    float4 pr4b = pred[base4 + 2 * HW4 + 1];
    float4 pb4a = pred[base4 + 3 * HW4];
    float4 pb4b = pred[base4 + 3 * HW4 + 1];
    float4 tl4a = tgt[base4];
    float4 tl4b = tgt[base4 + 1];
    float4 tt4a = tgt[base4 + HW4];
    float4 tt4b = tgt[base4 + HW4 + 1];
    float4 tr4a = tgt[base4 + 2 * HW4];
    float4 tr4b = tgt[base4 + 2 * HW4 + 1];
    float4 tb4a = tgt[base4 + 3 * HW4];
    float4 tb4b = tgt[base4 + 3 * HW4 + 1];
    int4   mka  = mask[m4];
    int4   mkb  = mask[m4 + 1];

    float ls = 0.0f, ms = 0.0f;
    ciou_elem(cx0 + 0*STRIDE_F, cy, pl4a.x, pt4a.x, pr4a.x, pb4a.x,
              tl4a.x, tt4a.x, tr4a.x, tb4a.x, mka.x, ls, ms);
    ciou_elem(cx0 + 1*STRIDE_F, cy, pl4a.y, pt4a.y, pr4a.y, pb4a.y,
              tl4a.y, tt4a.y, tr4a.y, tb4a.y, mka.y, ls, ms);
    ciou_elem(cx0 + 2*STRIDE_F, cy, pl4a.z, pt4a.z, pr4a.z, pb4a.z,
              tl4a.z, tt4a.z, tr4a.z, tb4a.z, mka.z, ls, ms);
    ciou_elem(cx0 + 3*STRIDE_F, cy, pl4a.w, pt4a.w, pr4a.w, pb4a.w,
              tl4a.w, tt4a.w, tr4a.w, tb4a.w, mka.w, ls, ms);
    ciou_elem(cx0 + 4*STRIDE_F, cy, pl4b.x, pt4b.x, pr4b.x, pb4b.x,
              tl4b.x, tt4b.x, tr4b.x, tb4b.x, mkb.x, ls, ms);
    ciou_elem(cx0 + 5*STRIDE_F, cy, pl4b.y, pt4b.y, pr4b.y, pb4b.y,
              tl4b.y, tt4b.y, tr4b.y, tb4b.y, mkb.y, ls, ms);
    ciou_elem(cx0 + 6*STRIDE_F, cy, pl4b.z, pt4b.z, pr4b.z, pb4b.z,
              tl4b.z, tt4b.z, tr4b.z, tb4b.z, mkb.z, ls, ms);
    ciou_elem(cx0 + 7*STRIDE_F, cy, pl4b.w, pt4b.w, pr4b.w, pb4b.w,
              tl4b.w, tt4b.w, tr4b.w, tb4b.w, mkb.w, ls, ms);

    // wave-64 reduction
    #pragma unroll
    for (int off = 32; off > 0; off >>= 1) {
        ls += __shfl_down(ls, off, 64);
        ms += __shfl_down(ms, off, 64);
    }
    __shared__ float s_l[4];
    __shared__ float s_m[4];
    __shared__ bool s_last;
    int wave = threadIdx.x >> 6;
    int lane = threadIdx.x & 63;
    if (lane == 0) { s_l[wave] = ls; s_m[wave] = ms; }
    __syncthreads();
    if (threadIdx.x == 0) {
        float2 p;
        p.x = s_l[0] + s_l[1] + s_l[2] + s_l[3];
        p.y = s_m[0] + s_m[1] + s_m[2] + s_m[3];
        parts[blockIdx.x] = p;
        __threadfence();   // make the partial visible device-wide before the ticket
        unsigned int old = atomicAdd(ticket, 1u);
        s_last = (old == (unsigned int)(NBLOCKS - 1));
    }
    __syncthreads();
    if (!s_last) return;

    // ----- last block: final reduction over all partials -----
    __threadfence();  // acquire: order the ticket read before partial reads
    float fl = 0.0f, fm = 0.0f;
    for (int i = threadIdx.x; i < NBLOCKS; i += 256) {
        unsigned long long u = __hip_atomic_load(
            (const unsigned long long*)&parts[i],
            __ATOMIC_RELAXED, __HIP_MEMORY_SCOPE_AGENT);
        union { unsigned long long u; float2 f; } cvt;
        cvt.u = u;
        fl += cvt.f.x;
        fm += cvt.f.y;
    }
    #pragma unroll
    for (int off = 32; off > 0; off >>= 1) {
        fl += __shfl_down(fl, off, 64);
        fm += __shfl_down(fm, off, 64);
    }
    __syncthreads();  // s_l/s_m reuse
    if (lane == 0) { s_l[wave] = fl; s_m[wave] = fm; }
    __syncthreads();
    if (threadIdx.x == 0) {
        float tls = s_l[0] + s_l[1] + s_l[2] + s_l[3];
        float tms = s_m[0] + s_m[1] + s_m[2] + s_m[3];
        out[0] = tls / fmaxf(tms, 1.0f);
    }
}

extern "C" void kernel_launch(void* const* d_in, const int* in_sizes, int n_in,
                              void* d_out, int out_size, void* d_ws, size_t ws_size,
                              hipStream_t stream) {
    const float4* pred = (const float4*)d_in[0];
    const float4* tgt  = (const float4*)d_in[1];
    const int4*   mask = (const int4*)d_in[2];
    float* out = (float*)d_out;

    float2* parts = (float2*)d_ws;
    unsigned int* ticket = (unsigned int*)((char*)d_ws + NBLOCKS * sizeof(float2));

    hipMemsetAsync(ticket, 0, sizeof(unsigned int), stream);

    ciou_loss_kernel<<<NBLOCKS, 256, 0, stream>>>(pred, tgt, mask, parts, ticket, out);
}

// Round 6
// 113.413 us; speedup vs baseline: 1.3751x; 1.3751x over previous
//
#include <hip/hip_runtime.h>
#include <hip/hip_bf16.h>
#include <math.h>

// Problem constants: B=64, H=192, W=192, STRIDE=8, EPS=1e-7
// R4 journal: fusing the final reduce via ticket+__threadfence regressed the
// main kernel 25->70us (device-scope fence per block serializes at TCC).
// Two-kernel structure restored. R5: NT loads need clang ext_vector types,
// not HIP_vector_type structs.
#define STRIDE_F 8.0f
#define EPS_F 1e-7f
#define PI_2_F 1.57079632679489662f

typedef float vf4 __attribute__((ext_vector_type(4)));
typedef int   vi4 __attribute__((ext_vector_type(4)));

__device__ __forceinline__ float frcp(float x) { return __builtin_amdgcn_rcpf(x); }

// atan(w/h) for w >= 0, h > 0, branch-free min/max range reduction,
// degree-11 odd minimax poly, max err ~1e-5 rad (tolerance is 1.56e-2).
__device__ __forceinline__ float fast_atan_ratio(float w, float h)
{
    float num = fminf(w, h);
    float den = fmaxf(w, h);
    float z   = num * frcp(den);
    float z2  = z * z;
    float p = fmaf(z2, -0.0117212f,  0.05265332f);
    p = fmaf(z2, p, -0.11643287f);
    p = fmaf(z2, p,  0.19354346f);
    p = fmaf(z2, p, -0.33262347f);
    p = fmaf(z2, p,  0.99997726f);
    p = z * p;
    return (w > h) ? (PI_2_F - p) : p;
}

__device__ __forceinline__ void ciou_elem(
    float cx, float cy,
    float pl, float pt, float pr, float pb,
    float tl, float tt, float tr, float tb,
    int m_i, float& ls, float& ms)
{
    float px1 = cx - pl * STRIDE_F;
    float py1 = cy - pt * STRIDE_F;
    float px2 = cx + pr * STRIDE_F;
    float py2 = cy + pb * STRIDE_F;
    float tx1 = cx - tl * STRIDE_F;
    float ty1 = cy - tt * STRIDE_F;
    float tx2 = cx + tr * STRIDE_F;
    float ty2 = cy + tb * STRIDE_F;

    float w1 = px2 - px1, h1 = py2 - py1;
    float w2 = tx2 - tx1, h2 = ty2 - ty1;
    float iw = fmaxf(fminf(px2, tx2) - fmaxf(px1, tx1), 0.0f);
    float ih = fmaxf(fminf(py2, ty2) - fmaxf(py1, ty1), 0.0f);
    float inter = iw * ih;
    float uni   = w1 * h1 + w2 * h2 - inter + EPS_F;
    float iou   = inter * frcp(uni);

    float cw = fmaxf(px2, tx2) - fminf(px1, tx1);
    float ch = fmaxf(py2, ty2) - fminf(py1, ty1);
    float c2 = cw * cw + ch * ch + EPS_F;

    float dx = tx1 + tx2 - px1 - px2;
    float dy = ty1 + ty2 - py1 - py2;
    float rho2 = (dx * dx + dy * dy) * 0.25f;

    const float FOUR_OVER_PI2 = 0.40528473456935109f; // 4/pi^2
    float dv = fast_atan_ratio(w2, h2 + EPS_F) - fast_atan_ratio(w1, h1 + EPS_F);
    float v  = FOUR_OVER_PI2 * dv * dv;
    float alpha = v * frcp(v - iou + (1.0f + EPS_F));
    float ciou  = iou - rho2 * frcp(c2) - alpha * v;

    float m = (m_i != 0) ? 1.0f : 0.0f;
    ls += (1.0f - ciou) * m;
    ms += m;
}

__global__ __launch_bounds__(256) void ciou_loss_kernel(
    const vf4* __restrict__ pred, const vf4* __restrict__ tgt,
    const vi4* __restrict__ mask, float2* __restrict__ parts,
    int HW4, int W4)
{
    int idx4 = blockIdx.x * blockDim.x + threadIdx.x;
    // exact launch: grid*block == total/4, no bounds check needed
    int bb  = idx4 / HW4;
    int hw4 = idx4 - bb * HW4;
    int h   = hw4 / W4;
    int w4  = hw4 - h * W4;

    float cy = ((float)h + 0.5f) * STRIDE_F;
    float cx0 = ((float)(w4 * 4) + 0.5f) * STRIDE_F;

    size_t base = (size_t)bb * 4 * (size_t)HW4 + (size_t)hw4;
    // Streaming read-once inputs: non-temporal loads skip cache fill.
    vf4 pl4 = __builtin_nontemporal_load(&pred[base]);
    vf4 pt4 = __builtin_nontemporal_load(&pred[base + (size_t)HW4]);
    vf4 pr4 = __builtin_nontemporal_load(&pred[base + 2 * (size_t)HW4]);
    vf4 pb4 = __builtin_nontemporal_load(&pred[base + 3 * (size_t)HW4]);
    vf4 tl4 = __builtin_nontemporal_load(&tgt[base]);
    vf4 tt4 = __builtin_nontemporal_load(&tgt[base + (size_t)HW4]);
    vf4 tr4 = __builtin_nontemporal_load(&tgt[base + 2 * (size_t)HW4]);
    vf4 tb4 = __builtin_nontemporal_load(&tgt[base + 3 * (size_t)HW4]);
    vi4 mk4 = __builtin_nontemporal_load(&mask[idx4]);

    float ls = 0.0f, ms = 0.0f;
    ciou_elem(cx0 + 0.0f * STRIDE_F, cy, pl4.x, pt4.x, pr4.x, pb4.x,
              tl4.x, tt4.x, tr4.x, tb4.x, mk4.x, ls, ms);
    ciou_elem(cx0 + 1.0f * STRIDE_F, cy, pl4.y, pt4.y, pr4.y, pb4.y,
              tl4.y, tt4.y, tr4.y, tb4.y, mk4.y, ls, ms);
    ciou_elem(cx0 + 2.0f * STRIDE_F, cy, pl4.z, pt4.z, pr4.z, pb4.z,
              tl4.z, tt4.z, tr4.z, tb4.z, mk4.z, ls, ms);
    ciou_elem(cx0 + 3.0f * STRIDE_F, cy, pl4.w, pt4.w, pr4.w, pb4.w,
              tl4.w, tt4.w, tr4.w, tb4.w, mk4.w, ls, ms);

    // wave-64 reduction
    #pragma unroll
    for (int off = 32; off > 0; off >>= 1) {
        ls += __shfl_down(ls, off, 64);
        ms += __shfl_down(ms, off, 64);
    }
    __shared__ float s_l[4];
    __shared__ float s_m[4];
    int wave = threadIdx.x >> 6;
    int lane = threadIdx.x & 63;
    if (lane == 0) { s_l[wave] = ls; s_m[wave] = ms; }
    __syncthreads();
    if (threadIdx.x == 0) {
        float2 p;
        p.x = s_l[0] + s_l[1] + s_l[2] + s_l[3];
        p.y = s_m[0] + s_m[1] + s_m[2] + s_m[3];
        parts[blockIdx.x] = p;
    }
}

__global__ __launch_bounds__(256) void reduce_kernel(
    const float2* __restrict__ parts, int n, float* __restrict__ out)
{
    float ls = 0.0f, ms = 0.0f;
    for (int i = threadIdx.x; i < n; i += 256) {
        float2 p = parts[i];
        ls += p.x;
        ms += p.y;
    }
    #pragma unroll
    for (int off = 32; off > 0; off >>= 1) {
        ls += __shfl_down(ls, off, 64);
        ms += __shfl_down(ms, off, 64);
    }
    __shared__ float s_l[4];
    __shared__ float s_m[4];
    int wave = threadIdx.x >> 6;
    int lane = threadIdx.x & 63;
    if (lane == 0) { s_l[wave] = ls; s_m[wave] = ms; }
    __syncthreads();
    if (threadIdx.x == 0) {
        float tls = s_l[0] + s_l[1] + s_l[2] + s_l[3];
        float tms = s_m[0] + s_m[1] + s_m[2] + s_m[3];
        out[0] = tls / fmaxf(tms, 1.0f);
    }
}

extern "C" void kernel_launch(void* const* d_in, const int* in_sizes, int n_in,
                              void* d_out, int out_size, void* d_ws, size_t ws_size,
                              hipStream_t stream) {
    const vf4* pred = (const vf4*)d_in[0];
    const vf4* tgt  = (const vf4*)d_in[1];
    const vi4* mask = (const vi4*)d_in[2];
    float* out  = (float*)d_out;
    float2* parts = (float2*)d_ws;

    const int B = 64, H = 192, W = 192;
    const int HW = H * W;
    const int total4 = B * HW / 4;        // 589824
    const int threads = 256;
    const int blocks = total4 / threads;  // 2304, exact

    ciou_loss_kernel<<<blocks, threads, 0, stream>>>(pred, tgt, mask, parts,
                                                     HW / 4, W / 4);
    reduce_kernel<<<1, threads, 0, stream>>>(parts, blocks, out);
}

// Round 7
// 106.363 us; speedup vs baseline: 1.4662x; 1.0663x over previous
//
#include <hip/hip_runtime.h>
#include <hip/hip_bf16.h>
#include <math.h>

// Problem constants: B=64, H=192, W=192, STRIDE=8, EPS=1e-7
// Journal:
//  R1: same-address atomics serialized (239us). -> per-block partials.
//  R2: vec4 + partials: 107us. R3: fast-math (rcp/atan poly): 106us (neutral;
//      main kernel is memory-bound, not VALU).
//  R4: ticket+threadfence fusion REGRESSED (main 25->70us). Two kernels kept.
//  R6: nontemporal loads REGRESSED (106->113): harness restores inputs right
//      before launch, so they are L2/L3-warm; never bypass cache on reads here.
//  R7: pure revert to R3 config (best measured: 106.0us).
#define STRIDE_F 8.0f
#define EPS_F 1e-7f
#define PI_2_F 1.57079632679489662f

__device__ __forceinline__ float frcp(float x) { return __builtin_amdgcn_rcpf(x); }

// atan(w/h) for w >= 0, h > 0, branch-free min/max range reduction,
// degree-11 odd minimax poly, max err ~1e-5 rad (tolerance is 1.56e-2).
__device__ __forceinline__ float fast_atan_ratio(float w, float h)
{
    float num = fminf(w, h);
    float den = fmaxf(w, h);
    float z   = num * frcp(den);
    float z2  = z * z;
    float p = fmaf(z2, -0.0117212f,  0.05265332f);
    p = fmaf(z2, p, -0.11643287f);
    p = fmaf(z2, p,  0.19354346f);
    p = fmaf(z2, p, -0.33262347f);
    p = fmaf(z2, p,  0.99997726f);
    p = z * p;
    return (w > h) ? (PI_2_F - p) : p;
}

__device__ __forceinline__ void ciou_elem(
    float cx, float cy,
    float pl, float pt, float pr, float pb,
    float tl, float tt, float tr, float tb,
    int m_i, float& ls, float& ms)
{
    float px1 = cx - pl * STRIDE_F;
    float py1 = cy - pt * STRIDE_F;
    float px2 = cx + pr * STRIDE_F;
    float py2 = cy + pb * STRIDE_F;
    float tx1 = cx - tl * STRIDE_F;
    float ty1 = cy - tt * STRIDE_F;
    float tx2 = cx + tr * STRIDE_F;
    float ty2 = cy + tb * STRIDE_F;

    float w1 = px2 - px1, h1 = py2 - py1;
    float w2 = tx2 - tx1, h2 = ty2 - ty1;
    float iw = fmaxf(fminf(px2, tx2) - fmaxf(px1, tx1), 0.0f);
    float ih = fmaxf(fminf(py2, ty2) - fmaxf(py1, ty1), 0.0f);
    float inter = iw * ih;
    float uni   = w1 * h1 + w2 * h2 - inter + EPS_F;
    float iou   = inter * frcp(uni);

    float cw = fmaxf(px2, tx2) - fminf(px1, tx1);
    float ch = fmaxf(py2, ty2) - fminf(py1, ty1);
    float c2 = cw * cw + ch * ch + EPS_F;

    float dx = tx1 + tx2 - px1 - px2;
    float dy = ty1 + ty2 - py1 - py2;
    float rho2 = (dx * dx + dy * dy) * 0.25f;

    const float FOUR_OVER_PI2 = 0.40528473456935109f; // 4/pi^2
    float dv = fast_atan_ratio(w2, h2 + EPS_F) - fast_atan_ratio(w1, h1 + EPS_F);
    float v  = FOUR_OVER_PI2 * dv * dv;
    float alpha = v * frcp(v - iou + (1.0f + EPS_F));
    float ciou  = iou - rho2 * frcp(c2) - alpha * v;

    float m = (m_i != 0) ? 1.0f : 0.0f;
    ls += (1.0f - ciou) * m;
    ms += m;
}

__global__ __launch_bounds__(256) void ciou_loss_kernel(
    const float4* __restrict__ pred, const float4* __restrict__ tgt,
    const int4* __restrict__ mask, float2* __restrict__ parts,
    int HW4, int W4)
{
    int idx4 = blockIdx.x * blockDim.x + threadIdx.x;
    // exact launch: grid*block == total/4, no bounds check needed
    int bb  = idx4 / HW4;
    int hw4 = idx4 - bb * HW4;
    int h   = hw4 / W4;
    int w4  = hw4 - h * W4;

    float cy = ((float)h + 0.5f) * STRIDE_F;
    float cx0 = ((float)(w4 * 4) + 0.5f) * STRIDE_F;

    size_t base = (size_t)bb * 4 * (size_t)HW4 + (size_t)hw4;
    float4 pl4 = pred[base];
    float4 pt4 = pred[base + (size_t)HW4];
    float4 pr4 = pred[base + 2 * (size_t)HW4];
    float4 pb4 = pred[base + 3 * (size_t)HW4];
    float4 tl4 = tgt[base];
    float4 tt4 = tgt[base + (size_t)HW4];
    float4 tr4 = tgt[base + 2 * (size_t)HW4];
    float4 tb4 = tgt[base + 3 * (size_t)HW4];
    int4   mk4 = mask[idx4];

    float ls = 0.0f, ms = 0.0f;
    ciou_elem(cx0 + 0.0f * STRIDE_F, cy, pl4.x, pt4.x, pr4.x, pb4.x,
              tl4.x, tt4.x, tr4.x, tb4.x, mk4.x, ls, ms);
    ciou_elem(cx0 + 1.0f * STRIDE_F, cy, pl4.y, pt4.y, pr4.y, pb4.y,
              tl4.y, tt4.y, tr4.y, tb4.y, mk4.y, ls, ms);
    ciou_elem(cx0 + 2.0f * STRIDE_F, cy, pl4.z, pt4.z, pr4.z, pb4.z,
              tl4.z, tt4.z, tr4.z, tb4.z, mk4.z, ls, ms);
    ciou_elem(cx0 + 3.0f * STRIDE_F, cy, pl4.w, pt4.w, pr4.w, pb4.w,
              tl4.w, tt4.w, tr4.w, tb4.w, mk4.w, ls, ms);

    // wave-64 reduction
    #pragma unroll
    for (int off = 32; off > 0; off >>= 1) {
        ls += __shfl_down(ls, off, 64);
        ms += __shfl_down(ms, off, 64);
    }
    __shared__ float s_l[4];
    __shared__ float s_m[4];
    int wave = threadIdx.x >> 6;
    int lane = threadIdx.x & 63;
    if (lane == 0) { s_l[wave] = ls; s_m[wave] = ms; }
    __syncthreads();
    if (threadIdx.x == 0) {
        float2 p;
        p.x = s_l[0] + s_l[1] + s_l[2] + s_l[3];
        p.y = s_m[0] + s_m[1] + s_m[2] + s_m[3];
        parts[blockIdx.x] = p;
    }
}

__global__ __launch_bounds__(256) void reduce_kernel(
    const float2* __restrict__ parts, int n, float* __restrict__ out)
{
    float ls = 0.0f, ms = 0.0f;
    for (int i = threadIdx.x; i < n; i += 256) {
        float2 p = parts[i];
        ls += p.x;
        ms += p.y;
    }
    #pragma unroll
    for (int off = 32; off > 0; off >>= 1) {
        ls += __shfl_down(ls, off, 64);
        ms += __shfl_down(ms, off, 64);
    }
    __shared__ float s_l[4];
    __shared__ float s_m[4];
    int wave = threadIdx.x >> 6;
    int lane = threadIdx.x & 63;
    if (lane == 0) { s_l[wave] = ls; s_m[wave] = ms; }
    __syncthreads();
    if (threadIdx.x == 0) {
        float tls = s_l[0] + s_l[1] + s_l[2] + s_l[3];
        float tms = s_m[0] + s_m[1] + s_m[2] + s_m[3];
        out[0] = tls / fmaxf(tms, 1.0f);
    }
}

extern "C" void kernel_launch(void* const* d_in, const int* in_sizes, int n_in,
                              void* d_out, int out_size, void* d_ws, size_t ws_size,
                              hipStream_t stream) {
    const float4* pred = (const float4*)d_in[0];
    const float4* tgt  = (const float4*)d_in[1];
    const int4*   mask = (const int4*)d_in[2];
    float* out  = (float*)d_out;
    float2* parts = (float2*)d_ws;

    const int B = 64, H = 192, W = 192;
    const int HW = H * W;
    const int total4 = B * HW / 4;        // 589824
    const int threads = 256;
    const int blocks = total4 / threads;  // 2304, exact

    ciou_loss_kernel<<<blocks, threads, 0, stream>>>(pred, tgt, mask, parts,
                                                     HW / 4, W / 4);
    reduce_kernel<<<1, threads, 0, stream>>>(parts, blocks, out);
}

// Round 8
// 106.107 us; speedup vs baseline: 1.4698x; 1.0024x over previous
//
#include <hip/hip_runtime.h>
#include <hip/hip_bf16.h>
#include <math.h>

// Problem constants: B=64, H=192, W=192, STRIDE=8, EPS=1e-7
// Journal:
//  R1: same-address atomics serialized (239us). -> per-block partials.
//  R2: vec4 + partials: 107us. R3: fast-math (rcp/atan poly): 106us (neutral).
//  R4: 8elem+ticket fusion REGRESSED (main 25->70us) - fence blamed, untested.
//  R6: nontemporal loads REGRESSED (106->113): inputs are L2/L3-warm.
//  R7: revert = 106.4us stable.
//  R8: isolate R4's other variable: 8 elem/thread, two-kernel, NO fence.
//      Two float4 iterations spaced 256 apart keeps every wave access a
//      contiguous 1KB segment.
#define STRIDE_F 8.0f
#define EPS_F 1e-7f
#define PI_2_F 1.57079632679489662f

__device__ __forceinline__ float frcp(float x) { return __builtin_amdgcn_rcpf(x); }

// atan(w/h) for w >= 0, h > 0, branch-free min/max range reduction,
// degree-11 odd minimax poly, max err ~1e-5 rad (tolerance is 1.56e-2).
__device__ __forceinline__ float fast_atan_ratio(float w, float h)
{
    float num = fminf(w, h);
    float den = fmaxf(w, h);
    float z   = num * frcp(den);
    float z2  = z * z;
    float p = fmaf(z2, -0.0117212f,  0.05265332f);
    p = fmaf(z2, p, -0.11643287f);
    p = fmaf(z2, p,  0.19354346f);
    p = fmaf(z2, p, -0.33262347f);
    p = fmaf(z2, p,  0.99997726f);
    p = z * p;
    return (w > h) ? (PI_2_F - p) : p;
}

__device__ __forceinline__ void ciou_elem(
    float cx, float cy,
    float pl, float pt, float pr, float pb,
    float tl, float tt, float tr, float tb,
    int m_i, float& ls, float& ms)
{
    float px1 = cx - pl * STRIDE_F;
    float py1 = cy - pt * STRIDE_F;
    float px2 = cx + pr * STRIDE_F;
    float py2 = cy + pb * STRIDE_F;
    float tx1 = cx - tl * STRIDE_F;
    float ty1 = cy - tt * STRIDE_F;
    float tx2 = cx + tr * STRIDE_F;
    float ty2 = cy + tb * STRIDE_F;

    float w1 = px2 - px1, h1 = py2 - py1;
    float w2 = tx2 - tx1, h2 = ty2 - ty1;
    float iw = fmaxf(fminf(px2, tx2) - fmaxf(px1, tx1), 0.0f);
    float ih = fmaxf(fminf(py2, ty2) - fmaxf(py1, ty1), 0.0f);
    float inter = iw * ih;
    float uni   = w1 * h1 + w2 * h2 - inter + EPS_F;
    float iou   = inter * frcp(uni);

    float cw = fmaxf(px2, tx2) - fminf(px1, tx1);
    float ch = fmaxf(py2, ty2) - fminf(py1, ty1);
    float c2 = cw * cw + ch * ch + EPS_F;

    float dx = tx1 + tx2 - px1 - px2;
    float dy = ty1 + ty2 - py1 - py2;
    float rho2 = (dx * dx + dy * dy) * 0.25f;

    const float FOUR_OVER_PI2 = 0.40528473456935109f; // 4/pi^2
    float dv = fast_atan_ratio(w2, h2 + EPS_F) - fast_atan_ratio(w1, h1 + EPS_F);
    float v  = FOUR_OVER_PI2 * dv * dv;
    float alpha = v * frcp(v - iou + (1.0f + EPS_F));
    float ciou  = iou - rho2 * frcp(c2) - alpha * v;

    float m = (m_i != 0) ? 1.0f : 0.0f;
    ls += (1.0f - ciou) * m;
    ms += m;
}

// Process one float4 worth (4 elements) given a flat float4 index.
__device__ __forceinline__ void ciou_vec4(
    const float4* __restrict__ pred, const float4* __restrict__ tgt,
    const int4* __restrict__ mask, int idx4, int HW4, int W4,
    float& ls, float& ms)
{
    int bb  = idx4 / HW4;
    int hw4 = idx4 - bb * HW4;
    int h   = hw4 / W4;
    int w4  = hw4 - h * W4;

    float cy  = ((float)h + 0.5f) * STRIDE_F;
    float cx0 = ((float)(w4 * 4) + 0.5f) * STRIDE_F;

    size_t base = (size_t)bb * 4 * (size_t)HW4 + (size_t)hw4;
    float4 pl4 = pred[base];
    float4 pt4 = pred[base + (size_t)HW4];
    float4 pr4 = pred[base + 2 * (size_t)HW4];
    float4 pb4 = pred[base + 3 * (size_t)HW4];
    float4 tl4 = tgt[base];
    float4 tt4 = tgt[base + (size_t)HW4];
    float4 tr4 = tgt[base + 2 * (size_t)HW4];
    float4 tb4 = tgt[base + 3 * (size_t)HW4];
    int4   mk4 = mask[idx4];

    ciou_elem(cx0 + 0.0f * STRIDE_F, cy, pl4.x, pt4.x, pr4.x, pb4.x,
              tl4.x, tt4.x, tr4.x, tb4.x, mk4.x, ls, ms);
    ciou_elem(cx0 + 1.0f * STRIDE_F, cy, pl4.y, pt4.y, pr4.y, pb4.y,
              tl4.y, tt4.y, tr4.y, tb4.y, mk4.y, ls, ms);
    ciou_elem(cx0 + 2.0f * STRIDE_F, cy, pl4.z, pt4.z, pr4.z, pb4.z,
              tl4.z, tt4.z, tr4.z, tb4.z, mk4.z, ls, ms);
    ciou_elem(cx0 + 3.0f * STRIDE_F, cy, pl4.w, pt4.w, pr4.w, pb4.w,
              tl4.w, tt4.w, tr4.w, tb4.w, mk4.w, ls, ms);
}

__global__ __launch_bounds__(256) void ciou_loss_kernel(
    const float4* __restrict__ pred, const float4* __restrict__ tgt,
    const int4* __restrict__ mask, float2* __restrict__ parts,
    int HW4, int W4)
{
    // 1152 blocks x 256 threads x 2 float4 iterations = 589824 float4s, exact.
    int idx4a = blockIdx.x * 512 + threadIdx.x;        // first 1KB-contig chunk
    int idx4b = idx4a + 256;                           // second chunk

    float ls = 0.0f, ms = 0.0f;
    ciou_vec4(pred, tgt, mask, idx4a, HW4, W4, ls, ms);
    ciou_vec4(pred, tgt, mask, idx4b, HW4, W4, ls, ms);

    // wave-64 reduction
    #pragma unroll
    for (int off = 32; off > 0; off >>= 1) {
        ls += __shfl_down(ls, off, 64);
        ms += __shfl_down(ms, off, 64);
    }
    __shared__ float s_l[4];
    __shared__ float s_m[4];
    int wave = threadIdx.x >> 6;
    int lane = threadIdx.x & 63;
    if (lane == 0) { s_l[wave] = ls; s_m[wave] = ms; }
    __syncthreads();
    if (threadIdx.x == 0) {
        float2 p;
        p.x = s_l[0] + s_l[1] + s_l[2] + s_l[3];
        p.y = s_m[0] + s_m[1] + s_m[2] + s_m[3];
        parts[blockIdx.x] = p;
    }
}

__global__ __launch_bounds__(256) void reduce_kernel(
    const float2* __restrict__ parts, int n, float* __restrict__ out)
{
    float ls = 0.0f, ms = 0.0f;
    for (int i = threadIdx.x; i < n; i += 256) {
        float2 p = parts[i];
        ls += p.x;
        ms += p.y;
    }
    #pragma unroll
    for (int off = 32; off > 0; off >>= 1) {
        ls += __shfl_down(ls, off, 64);
        ms += __shfl_down(ms, off, 64);
    }
    __shared__ float s_l[4];
    __shared__ float s_m[4];
    int wave = threadIdx.x >> 6;
    int lane = threadIdx.x & 63;
    if (lane == 0) { s_l[wave] = ls; s_m[wave] = ms; }
    __syncthreads();
    if (threadIdx.x == 0) {
        float tls = s_l[0] + s_l[1] + s_l[2] + s_l[3];
        float tms = s_m[0] + s_m[1] + s_m[2] + s_m[3];
        out[0] = tls / fmaxf(tms, 1.0f);
    }
}

extern "C" void kernel_launch(void* const* d_in, const int* in_sizes, int n_in,
                              void* d_out, int out_size, void* d_ws, size_t ws_size,
                              hipStream_t stream) {
    const float4* pred = (const float4*)d_in[0];
    const float4* tgt  = (const float4*)d_in[1];
    const int4*   mask = (const int4*)d_in[2];
    float* out  = (float*)d_out;
    float2* parts = (float2*)d_ws;

    const int B = 64, H = 192, W = 192;
    const int HW = H * W;
    const int total4 = B * HW / 4;            // 589824
    const int threads = 256;
    const int blocks = total4 / (threads * 2); // 1152, exact

    ciou_loss_kernel<<<blocks, threads, 0, stream>>>(pred, tgt, mask, parts,
                                                     HW / 4, W / 4);
    reduce_kernel<<<1, threads, 0, stream>>>(parts, blocks, out);
}